// Round 4
// baseline (228.488 us; speedup 1.0000x reference)
//
#include <hip/hip_runtime.h>
#include <cstdint>
#include <cstddef>

#define S_LEN 4096
#define NB 8
#define NH 12
#define DMODEL 768
#define DHEAD 64
#define M_TOT (NB * S_LEN)      /* 32768 */
#define INV_SQRT_DH 0.125f
#define WSZ (DMODEL * DMODEL)

typedef __attribute__((ext_vector_type(4))) float f32x4;
typedef __attribute__((ext_vector_type(8))) short bf16x8;

__device__ inline float bf2f(unsigned short h) {
    union { unsigned int u; float f; } v; v.u = ((unsigned int)h) << 16; return v.f;
}
__device__ inline unsigned short f2bf(float f) {
    union { float f; unsigned int u; } v; v.f = f;
    unsigned int r = v.u + 0x7FFFu + ((v.u >> 16) & 1u);
    return (unsigned short)(r >> 16);
}

__device__ inline void gload_lds16(const unsigned short* gp, void* lp) {
    __builtin_amdgcn_global_load_lds((const __attribute__((address_space(1))) void*)gp,
                                     (__attribute__((address_space(3))) void*)lp,
                                     16, 0, 0);
}

// ---------------- prep: hs cvt + all weights/biases, one launch ----------------
__global__ void prep_all(const float* __restrict__ hs,
                         const float* __restrict__ Wq, const float* __restrict__ Wk,
                         const float* __restrict__ Wt, const float* __restrict__ Wqa,
                         const float* __restrict__ bq, const float* __restrict__ bk,
                         unsigned short* __restrict__ hs_bf,
                         unsigned short* __restrict__ Wqk_bf, unsigned short* __restrict__ Wt_bf,
                         unsigned short* __restrict__ Wqa_bf, float* __restrict__ bqk) {
    int bid = blockIdx.x;
    int t = threadIdx.x;
    if (bid < 24576) {
        int off = bid * 1024 + t * 4;
        float4 v = *(const float4*)(hs + off);
        ushort4 o;
        o.x = f2bf(v.x); o.y = f2bf(v.y); o.z = f2bf(v.z); o.w = f2bf(v.w);
        *(ushort4*)(hs_bf + off) = o;
        return;
    }
    bid -= 24576;
    if (bid < 1728) {
        const float* src = (bid < 576) ? Wq : ((bid < 1152) ? Wk : Wt);
        unsigned short* dst = (bid < 576) ? Wqk_bf : ((bid < 1152) ? (Wqk_bf + WSZ) : Wt_bf);
        int off = (bid % 576) * 1024 + t * 4;
        float4 v = *(const float4*)(src + off);
        ushort4 o;
        o.x = f2bf(v.x); o.y = f2bf(v.y); o.z = f2bf(v.z); o.w = f2bf(v.w);
        *(ushort4*)(dst + off) = o;
    } else if (bid < 1740) {
        int off = (bid - 1728) * 1024 + t * 4;
        int h = off / DMODEL;
        ushort4 o = {0, 0, 0, 0};
        if (h < NH) {
            float4 v = *(const float4*)(Wqa + off);
            o.x = f2bf(v.x); o.y = f2bf(v.y); o.z = f2bf(v.z); o.w = f2bf(v.w);
        }
        *(ushort4*)(Wqa_bf + off) = o;
    } else {
        int off = (bid - 1740) * 1024 + t * 4;
        if (off < 2 * DMODEL) {
            const float* src = (off < DMODEL) ? (bq + off) : (bk + off - DMODEL);
            *(float4*)(bqk + off) = *(const float4*)src;
        }
    }
}

// ---------------- shared phase macros ----------------
#define PH_MID() do { __builtin_amdgcn_s_barrier(); \
    asm volatile("s_waitcnt lgkmcnt(0)"); \
    __builtin_amdgcn_sched_barrier(0); \
    __builtin_amdgcn_s_setprio(1); } while (0)
#define PH_END() do { __builtin_amdgcn_s_setprio(0); \
    __builtin_amdgcn_s_barrier(); } while (0)

// ================= GEMM A: 256x256, 8-load/K-tile (qk projection) =================
#define STG_A(q, kt, BO) gload_lds16(pA + (size_t)((q) * 64) * 768 + (kt) * 64, \
                                     lds + (BO) + (q) * 8192 + wOff)
#define STG_B(q, kt, BO) gload_lds16(pB + (size_t)((q) * 64) * 768 + (kt) * 64, \
                                     lds + (BO) + 32768 + (q) * 8192 + wOff)

#define LD_A(mh, BO) do { _Pragma("unroll") for (int mm = 0; mm < 4; ++mm) { \
    a[mm][0] = *(const bf16x8*)(lds + (BO) + aRd0 + ((mh) * 4 + mm) * 2048); \
    a[mm][1] = *(const bf16x8*)(lds + (BO) + aRd1 + ((mh) * 4 + mm) * 2048); } } while (0)
#define LD_B(nh, BO) do { _Pragma("unroll") for (int nn = 0; nn < 2; ++nn) { \
    b[(nh) * 2 + nn][0] = *(const bf16x8*)(lds + (BO) + bRd0 + ((nh) * 2 + nn) * 2048); \
    b[(nh) * 2 + nn][1] = *(const bf16x8*)(lds + (BO) + bRd1 + ((nh) * 2 + nn) * 2048); } } while (0)
#define MFMAQ(mh, nh) do { _Pragma("unroll") for (int mm = 0; mm < 4; ++mm) \
    _Pragma("unroll") for (int nn = 0; nn < 2; ++nn) { \
        acc[(mh) * 4 + mm][(nh) * 2 + nn] = __builtin_amdgcn_mfma_f32_16x16x32_bf16( \
            a[mm][0], b[(nh) * 2 + nn][0], acc[(mh) * 4 + mm][(nh) * 2 + nn], 0, 0, 0); \
        acc[(mh) * 4 + mm][(nh) * 2 + nn] = __builtin_amdgcn_mfma_f32_16x16x32_bf16( \
            a[mm][1], b[(nh) * 2 + nn][1], acc[(mh) * 4 + mm][(nh) * 2 + nn], 0, 0, 0); } } while (0)

__global__ __launch_bounds__(512, 2) void gemm8(
    const unsigned short* __restrict__ A,
    const unsigned short* __restrict__ Bw,
    const float* __restrict__ bias,
    unsigned short* __restrict__ outBf, int ldoBf,
    int ntn)
{
    __shared__ __align__(16) char lds[131072];

    int nwg = gridDim.x;
    int bid = blockIdx.x;
    int cpx = nwg >> 3;
    int swz = (bid & 7) * cpx + (bid >> 3);
    int bidn = swz % ntn, bidm = swz / ntn;
    int m0 = bidm * 256, n0 = bidn * 256;

    int t = threadIdx.x;
    int w = t >> 6, lane = t & 63;
    int lr = lane & 15, lk = lane >> 4;
    int wr = w >> 2, wc = w & 3;
    int wOff = w << 10;

    int srow = t >> 3;
    int sblk = (t & 7) ^ (srow & 7);
    const unsigned short* pA = A + (size_t)(m0 + srow) * 768 + sblk * 8;
    const unsigned short* pB = Bw + (size_t)(n0 + srow) * 768 + sblk * 8;

    int sx = lr & 7;
    int aRd0 = (wr * 128 + lr) * 128 + ((0 + lk) ^ sx) * 16;
    int aRd1 = (wr * 128 + lr) * 128 + ((4 + lk) ^ sx) * 16;
    int bRd0 = 32768 + (wc * 64 + lr) * 128 + ((0 + lk) ^ sx) * 16;
    int bRd1 = 32768 + (wc * 64 + lr) * 128 + ((4 + lk) ^ sx) * 16;

    f32x4 acc[8][4];
#pragma unroll
    for (int m = 0; m < 8; ++m)
#pragma unroll
        for (int n = 0; n < 4; ++n)
            acc[m][n] = (f32x4){0.f, 0.f, 0.f, 0.f};
    bf16x8 a[4][2], b[4][2];

    STG_A(0, 0, 0); STG_A(1, 0, 0); STG_A(2, 0, 0); STG_A(3, 0, 0);
    STG_B(0, 0, 0); STG_B(1, 0, 0); STG_B(2, 0, 0); STG_B(3, 0, 0);
    STG_A(0, 1, 65536); STG_A(2, 1, 65536);
    STG_B(0, 1, 65536); STG_B(1, 1, 65536); STG_B(2, 1, 65536); STG_B(3, 1, 65536);
    asm volatile("s_waitcnt vmcnt(6)");
    __builtin_amdgcn_s_barrier();

    for (int i = 0; i < 6; ++i) {
        int ktE = 2 * i, ktO = 2 * i + 1;
        int s2 = (i < 5);
        LD_A(0, 0); LD_B(0, 0);
        STG_A(1, ktO, 65536); STG_A(3, ktO, 65536);
        PH_MID(); MFMAQ(0, 0); PH_END();
        LD_B(1, 0);
        if (s2) { STG_A(0, ktE + 2, 0); STG_A(2, ktE + 2, 0); }
        PH_MID(); MFMAQ(0, 1); PH_END();
        LD_A(1, 0);
        if (s2) { STG_B(0, ktE + 2, 0); STG_B(1, ktE + 2, 0); }
        PH_MID(); MFMAQ(1, 1); PH_END();
        if (s2) { STG_B(2, ktE + 2, 0); STG_B(3, ktE + 2, 0); }
        PH_MID(); MFMAQ(1, 0);
        __builtin_amdgcn_s_setprio(0);
        if (s2) { asm volatile("s_waitcnt vmcnt(6)"); }
        else    { asm volatile("s_waitcnt vmcnt(0)"); }
        __builtin_amdgcn_s_barrier();
        LD_A(0, 65536); LD_B(0, 65536);
        if (s2) { STG_A(1, ktE + 2, 0); STG_A(3, ktE + 2, 0); }
        PH_MID(); MFMAQ(0, 0); PH_END();
        LD_B(1, 65536);
        if (s2) { STG_A(0, ktO + 2, 65536); STG_A(2, ktO + 2, 65536); }
        PH_MID(); MFMAQ(0, 1); PH_END();
        LD_A(1, 65536);
        if (s2) { STG_B(0, ktO + 2, 65536); STG_B(1, ktO + 2, 65536); }
        PH_MID(); MFMAQ(1, 1); PH_END();
        if (s2) { STG_B(2, ktO + 2, 65536); STG_B(3, ktO + 2, 65536); }
        PH_MID(); MFMAQ(1, 0);
        __builtin_amdgcn_s_setprio(0);
        if (s2) { asm volatile("s_waitcnt vmcnt(6)"); }
        __builtin_amdgcn_s_barrier();
    }

#pragma unroll
    for (int m = 0; m < 8; ++m) {
        int gr0 = m0 + wr * 128 + m * 16 + lk * 4;
#pragma unroll
        for (int n = 0; n < 4; ++n) {
            int gc = n0 + wc * 64 + n * 16 + lr;
            float bv = bias[gc];
#pragma unroll
            for (int r = 0; r < 4; ++r) {
                int gr = gr0 + r;
                outBf[(size_t)gr * ldoBf + gc] = f2bf(acc[m][n][r] + bv);
            }
        }
    }
}

// ================= GEMM B: 256x128, 6-load/K-tile (output GEMM, f32+resid) =================
// A quads free: q0,q2 after ph1; q1,q3 after ph3; B free after ph0.
// Stage slots: ph0:{A1,A3(tO)} ph2:{A0,A2(tE+2)} ph3:{B(tE+2)} ph4:{A1,A3(tE+2)}
//              ph6:{A0,A2(tO+2)} ph7:{B(tO+2)}. Boundary vmcnt(4); tail vmcnt(0).
#define STG2_A(q, kt, BO) gload_lds16(pA + (size_t)((q) * 64) * 1536 + (kt) * 64, \
                                      lds + (BO) + (q) * 8192 + wOff)
#define STG2_B(q, kt, BO) gload_lds16(pB + (size_t)((q) * 64) * 768 + (kt) * 64, \
                                      lds + (BO) + 32768 + (q) * 8192 + wOff)
#define LD2_A(mp, BO) do { _Pragma("unroll") for (int mm = 0; mm < 2; ++mm) { \
    a[mm][0] = *(const bf16x8*)(lds + (BO) + aRd0 + (2 * (mp) + mm) * 2048); \
    a[mm][1] = *(const bf16x8*)(lds + (BO) + aRd1 + (2 * (mp) + mm) * 2048); } } while (0)
#define LD2_B(BO) do { _Pragma("unroll") for (int nn = 0; nn < 2; ++nn) { \
    b[nn][0] = *(const bf16x8*)(lds + (BO) + bRd0 + (nn) * 2048); \
    b[nn][1] = *(const bf16x8*)(lds + (BO) + bRd1 + (nn) * 2048); } } while (0)
#define MFMA2(mp) do { _Pragma("unroll") for (int mm = 0; mm < 2; ++mm) \
    _Pragma("unroll") for (int nn = 0; nn < 2; ++nn) { \
        acc[2 * (mp) + mm][nn] = __builtin_amdgcn_mfma_f32_16x16x32_bf16( \
            a[mm][0], b[nn][0], acc[2 * (mp) + mm][nn], 0, 0, 0); \
        acc[2 * (mp) + mm][nn] = __builtin_amdgcn_mfma_f32_16x16x32_bf16( \
            a[mm][1], b[nn][1], acc[2 * (mp) + mm][nn], 0, 0, 0); } } while (0)

__global__ __launch_bounds__(512, 2) void gemm8b(
    const unsigned short* __restrict__ A,      // q in qk_bf, ld 1536
    const unsigned short* __restrict__ W8,     // 8x[768][768] gated Wt
    const float* __restrict__ bias,
    float* __restrict__ outF,
    const unsigned short* __restrict__ resid)  // q, ld 1536
{
    __shared__ __align__(16) char lds[98304];

    int nwg = gridDim.x;                       // 768
    int bid = blockIdx.x;
    int cpx = nwg >> 3;
    int swz = (bid & 7) * cpx + (bid >> 3);
    int bidn = swz % 6, bidm = swz / 6;
    int m0 = bidm * 256, n0 = bidn * 128;

    const unsigned short* Bw = W8 + (size_t)(m0 >> 12) * WSZ;

    int t = threadIdx.x;
    int w = t >> 6, lane = t & 63;
    int lr = lane & 15, lk = lane >> 4;
    int wr = w >> 2, wc = w & 3;
    int wOff = w << 10;

    int srow = t >> 3;
    int sblk = (t & 7) ^ (srow & 7);
    const unsigned short* pA = A + (size_t)(m0 + srow) * 1536 + sblk * 8;
    const unsigned short* pB = Bw + (size_t)(n0 + srow) * 768 + sblk * 8;

    int sx = lr & 7;
    int aRd0 = (wr * 128 + lr) * 128 + ((0 + lk) ^ sx) * 16;
    int aRd1 = (wr * 128 + lr) * 128 + ((4 + lk) ^ sx) * 16;
    int bRd0 = 32768 + (wc * 32 + lr) * 128 + ((0 + lk) ^ sx) * 16;
    int bRd1 = 32768 + (wc * 32 + lr) * 128 + ((4 + lk) ^ sx) * 16;

    f32x4 acc[8][2];
#pragma unroll
    for (int m = 0; m < 8; ++m)
#pragma unroll
        for (int n = 0; n < 2; ++n)
            acc[m][n] = (f32x4){0.f, 0.f, 0.f, 0.f};
    bf16x8 a[2][2], b[2][2];

    // prologue: t0 full (6), t1 partial {A0,A2,B0,B1}
    STG2_A(0, 0, 0); STG2_A(1, 0, 0); STG2_A(2, 0, 0); STG2_A(3, 0, 0);
    STG2_B(0, 0, 0); STG2_B(1, 0, 0);
    STG2_A(0, 1, 49152); STG2_A(2, 1, 49152);
    STG2_B(0, 1, 49152); STG2_B(1, 1, 49152);
    asm volatile("s_waitcnt vmcnt(4)");
    __builtin_amdgcn_s_barrier();

    for (int i = 0; i < 6; ++i) {
        int ktE = 2 * i, ktO = 2 * i + 1;
        int s2 = (i < 5);
        // ph0
        LD2_A(0, 0); LD2_B(0);
        STG2_A(1, ktO, 49152); STG2_A(3, ktO, 49152);
        PH_MID(); MFMA2(0); PH_END();
        // ph1
        LD2_A(1, 0);
        PH_MID(); MFMA2(1); PH_END();
        // ph2
        LD2_A(2, 0);
        if (s2) { STG2_A(0, ktE + 2, 0); STG2_A(2, ktE + 2, 0); }
        PH_MID(); MFMA2(2); PH_END();
        // ph3
        LD2_A(3, 0);
        if (s2) { STG2_B(0, ktE + 2, 0); STG2_B(1, ktE + 2, 0); }
        PH_MID(); MFMA2(3);
        __builtin_amdgcn_s_setprio(0);
        if (s2) { asm volatile("s_waitcnt vmcnt(4)"); }
        else    { asm volatile("s_waitcnt vmcnt(0)"); }
        __builtin_amdgcn_s_barrier();
        // ph4
        LD2_A(0, 49152); LD2_B(49152);
        if (s2) { STG2_A(1, ktE + 2, 0); STG2_A(3, ktE + 2, 0); }
        PH_MID(); MFMA2(0); PH_END();
        // ph5
        LD2_A(1, 49152);
        PH_MID(); MFMA2(1); PH_END();
        // ph6
        LD2_A(2, 49152);
        if (s2) { STG2_A(0, ktO + 2, 49152); STG2_A(2, ktO + 2, 49152); }
        PH_MID(); MFMA2(2); PH_END();
        // ph7
        LD2_A(3, 49152);
        if (s2) { STG2_B(0, ktO + 2, 49152); STG2_B(1, ktO + 2, 49152); }
        PH_MID(); MFMA2(3);
        __builtin_amdgcn_s_setprio(0);
        if (s2) { asm volatile("s_waitcnt vmcnt(4)"); }
        __builtin_amdgcn_s_barrier();
    }

#pragma unroll
    for (int m = 0; m < 8; ++m) {
        int gr0 = m0 + wr * 128 + m * 16 + lk * 4;
#pragma unroll
        for (int n = 0; n < 2; ++n) {
            int gc = n0 + wc * 32 + n * 16 + lr;
            float bv = bias[gc];
#pragma unroll
            for (int r = 0; r < 4; ++r) {
                int gr = gr0 + r;
                float v = acc[m][n][r] + bv + bf2f(resid[(size_t)gr * 1536 + gc]);
                outF[(size_t)gr * DMODEL + gc] = v;
            }
        }
    }
}

// ================= fused qfs + pool1 =================
// grid 512 blocks x 256 thr; block = 64 consecutive s-rows (one batch).
// MFMA logits -> LDS -> per-head chunk softmax -> weighted partial pool (q L2-hot).
// parts1[bid][h][0..63]=sum exp*q ; [64]=m ; [65]=Z
__global__ __launch_bounds__(256) void qfspool_kernel(
    const unsigned short* __restrict__ q,      // ld 1536
    const unsigned short* __restrict__ wqa,    // [16][768] bf16 (rows>=12 zero)
    const float* __restrict__ bqa,
    const float* __restrict__ mask,
    float* __restrict__ parts1)                // [512][12][66]
{
    int bid = blockIdx.x;
    int m0 = bid * 64;
    int b = m0 >> 12;
    int t = threadIdx.x;
    int w = t >> 6, lane = t & 63;
    int lr = lane & 15, lk = lane >> 4;
    int m0w = m0 + w * 16;

    __shared__ float lgt[16][68];
    __shared__ float mz[12], zz[12];
    __shared__ float pl[12][2][64];

    f32x4 acc = (f32x4){0.f, 0.f, 0.f, 0.f};
    for (int k0 = 0; k0 < DMODEL; k0 += 32) {
        bf16x8 av = *(const bf16x8*)&q[(size_t)(m0w + lr) * 1536 + k0 + lk * 8];
        bf16x8 bv = *(const bf16x8*)&wqa[lr * DMODEL + k0 + lk * 8];
        acc = __builtin_amdgcn_mfma_f32_16x16x32_bf16(av, bv, acc, 0, 0, 0);
    }
    if (lr < NH) {
        float bv = bqa[lr];
#pragma unroll
        for (int r = 0; r < 4; ++r) {
            int row = w * 16 + lk * 4 + r;
            lgt[lr][row] = acc[r] * INV_SQRT_DH + bv + mask[b * S_LEN + ((m0 + row) & (S_LEN - 1))];
        }
    }
    __syncthreads();

    if (t < 192) {
        int h = t >> 4, idx = t & 15;
        float v0 = lgt[h][idx * 4 + 0], v1 = lgt[h][idx * 4 + 1];
        float v2 = lgt[h][idx * 4 + 2], v3 = lgt[h][idx * 4 + 3];
        float m = fmaxf(fmaxf(v0, v1), fmaxf(v2, v3));
        m = fmaxf(m, __shfl_xor(m, 1)); m = fmaxf(m, __shfl_xor(m, 2));
        m = fmaxf(m, __shfl_xor(m, 4)); m = fmaxf(m, __shfl_xor(m, 8));
        float e0 = __expf(v0 - m), e1 = __expf(v1 - m), e2 = __expf(v2 - m), e3 = __expf(v3 - m);
        lgt[h][idx * 4 + 0] = e0; lgt[h][idx * 4 + 1] = e1;
        lgt[h][idx * 4 + 2] = e2; lgt[h][idx * 4 + 3] = e3;
        float z = e0 + e1 + e2 + e3;
        z += __shfl_xor(z, 1); z += __shfl_xor(z, 2);
        z += __shfl_xor(z, 4); z += __shfl_xor(z, 8);
        if (idx == 0) { mz[h] = m; zz[h] = z; }
    }
    __syncthreads();

    if (t < 192) {
        int h = t >> 4, sub = t & 15, oct = sub >> 1, rg = sub & 1;
        const unsigned short* xp = q + (size_t)(m0 + rg * 32) * 1536 + h * DHEAD + oct * 8;
        float a8[8];
#pragma unroll
        for (int e = 0; e < 8; ++e) a8[e] = 0.f;
        for (int r = 0; r < 32; ++r) {
            float wg = lgt[h][rg * 32 + r];
            bf16x8 v = *(const bf16x8*)(xp + (size_t)r * 1536);
#pragma unroll
            for (int e = 0; e < 8; ++e) a8[e] += wg * bf2f((unsigned short)v[e]);
        }
#pragma unroll
        for (int e = 0; e < 8; ++e) pl[h][rg][oct * 8 + e] = a8[e];
    }
    __syncthreads();

    float* dst = parts1 + (size_t)bid * 12 * 66;
    if (t < 192) {
        int h = t >> 4, idx = t & 15;
#pragma unroll
        for (int j = 0; j < 4; ++j) {
            int d = idx * 4 + j;
            dst[h * 66 + d] = pl[h][0][d] + pl[h][1][d];
        }
        if (idx == 0) { dst[h * 66 + 64] = mz[h]; dst[h * 66 + 65] = zz[h]; }
    }
}

// ---------------- fused qks+pool2 ----------------
__global__ __launch_bounds__(256) void pool2_kernel(
    const float* __restrict__ parts1,          // [8b][64c][12][66]
    const unsigned short* __restrict__ qk,     // ld 1536, k at +768
    const float* __restrict__ mask,
    float* __restrict__ parts2)                // [96][8][72]
{
    int bid = blockIdx.x;
    int bh = bid >> 3, c = bid & 7;
    int b = bh / NH, h = bh % NH;
    int s0 = c * 512;
    int t = threadIdx.x;

    __shared__ float pq[64];
    __shared__ float w[512];
    __shared__ float red[8];
    __shared__ float part[4][64];

    if (t < 64) {
        float M1 = -1e30f;
        for (int cc = 0; cc < 64; ++cc)
            M1 = fmaxf(M1, parts1[((size_t)(b * 64 + cc) * 12 + h) * 66 + 64]);
        float Z1 = 0.f, a1 = 0.f;
        for (int cc = 0; cc < 64; ++cc) {
            const float* p1 = parts1 + ((size_t)(b * 64 + cc) * 12 + h) * 66;
            float f = __expf(p1[64] - M1);
            Z1 += f * p1[65];
            a1 += f * p1[t];
        }
        pq[t] = a1 / Z1;
    }
    __syncthreads();

    int dblk = t & 7, rgrp = t >> 3;
    float pq8[8];
#pragma unroll
    for (int e = 0; e < 8; ++e) pq8[e] = pq[dblk * 8 + e];

    const unsigned short* kp = qk + ((size_t)(b * S_LEN + s0)) * 1536 + DMODEL + h * DHEAD + dblk * 8;

    for (int j = 0; j < 16; ++j) {
        int r = j * 32 + rgrp;
        bf16x8 v = *(const bf16x8*)(kp + (size_t)r * 1536);
        float d = 0.f;
#pragma unroll
        for (int e = 0; e < 8; ++e) d += bf2f((unsigned short)v[e]) * pq8[e];
        d += __shfl_xor(d, 1); d += __shfl_xor(d, 2); d += __shfl_xor(d, 4);
        if (dblk == 0) w[r] = d * INV_SQRT_DH + mask[b * S_LEN + s0 + r];
    }
    __syncthreads();

    float l0 = w[t], l1 = w[t + 256];
    float m = fmaxf(l0, l1);
#pragma unroll
    for (int off = 32; off; off >>= 1) m = fmaxf(m, __shfl_xor(m, off));
    if ((t & 63) == 0) red[t >> 6] = m;
    __syncthreads();
    float M = fmaxf(fmaxf(red[0], red[1]), fmaxf(red[2], red[3]));
    float w0 = __expf(l0 - M), w1 = __expf(l1 - M);
    float z = w0 + w1;
#pragma unroll
    for (int off = 32; off; off >>= 1) z += __shfl_xor(z, off);
    if ((t & 63) == 0) red[4 + (t >> 6)] = z;
    __syncthreads();
    w[t] = w0; w[t + 256] = w1;
    __syncthreads();
    float Z = red[4] + red[5] + red[6] + red[7];

    float acc[8];
#pragma unroll
    for (int e = 0; e < 8; ++e) acc[e] = 0.f;
    for (int j = 0; j < 16; ++j) {
        int r = j * 32 + rgrp;
        bf16x8 v = *(const bf16x8*)(kp + (size_t)r * 1536);
        float wr = w[r];
#pragma unroll
        for (int e = 0; e < 8; ++e) acc[e] += wr * bf2f((unsigned short)v[e]);
    }
#pragma unroll
    for (int off = 8; off <= 32; off <<= 1)
#pragma unroll
        for (int e = 0; e < 8; ++e) acc[e] += __shfl_xor(acc[e], off);
    if ((t & 63) < 8) {
#pragma unroll
        for (int e = 0; e < 8; ++e) part[t >> 6][(t & 7) * 8 + e] = acc[e];
    }
    __syncthreads();
    float* dst = parts2 + ((size_t)bh * 8 + c) * 72;
    if (t < 64) dst[t] = part[0][t] + part[1][t] + part[2][t] + part[3][t];
    else if (t == 64) dst[64] = M;
    else if (t == 65) dst[65] = Z;
}

// ---------------- gated weights: W8[b] = Wt * pooled_k[b][col] ----------------
__global__ __launch_bounds__(256) void gatedw_kernel(
    const float* __restrict__ parts2,
    const unsigned short* __restrict__ Wt_bf,
    unsigned short* __restrict__ W8)
{
    int bid = blockIdx.x;
    int b = bid / 96, rg = bid % 96;
    int t = threadIdx.x;

    __shared__ float mhc[96], Mh[12], fac[96], zh[12], pk[768];

    if (t < 96) mhc[t] = parts2[((size_t)(b * NH + t / 8) * 8 + (t & 7)) * 72 + 64];
    __syncthreads();
    if (t < 12) {
        float M = -1e30f;
#pragma unroll
        for (int cc = 0; cc < 8; ++cc) M = fmaxf(M, mhc[t * 8 + cc]);
        Mh[t] = M;
    }
    __syncthreads();
    if (t < 96) fac[t] = __expf(mhc[t] - Mh[t / 8]);
    __syncthreads();
    if (t < 12) {
        float Zm = 0.f;
#pragma unroll
        for (int cc = 0; cc < 8; ++cc)
            Zm += fac[t * 8 + cc] * parts2[((size_t)(b * NH + t) * 8 + cc) * 72 + 65];
        zh[t] = Zm;
    }
    __syncthreads();
#pragma unroll
    for (int j = 0; j < 3; ++j) {
        int col = t + 256 * j;
        int h = col >> 6, d = col & 63;
        const float* p2 = parts2 + (size_t)(b * NH + h) * 8 * 72;
        float v = 0.f;
#pragma unroll
        for (int cc = 0; cc < 8; ++cc) v += fac[h * 8 + cc] * p2[cc * 72 + d];
        pk[col] = v / zh[h];
    }
    __syncthreads();
#pragma unroll
    for (int j = 0; j < 3; ++j) {
        int idx = j * 2048 + t * 8;
        int r = rg * 8 + idx / DMODEL, k = idx % DMODEL;
        bf16x8 wv = *(const bf16x8*)(Wt_bf + (size_t)r * DMODEL + k);
        bf16x8 o;
#pragma unroll
        for (int e = 0; e < 8; ++e)
            o[e] = (short)f2bf(bf2f((unsigned short)wv[e]) * pk[k + e]);
        *(bf16x8*)(W8 + (size_t)b * WSZ + (size_t)r * DMODEL + k) = o;
    }
}

// ---------------- launch ----------------
extern "C" void kernel_launch(void* const* d_in, const int* in_sizes, int n_in,
                              void* d_out, int out_size, void* d_ws, size_t ws_size,
                              hipStream_t stream) {
    const float* hs   = (const float*)d_in[0];
    const float* mask = (const float*)d_in[1];
    const float* Wq   = (const float*)d_in[2];
    const float* bq   = (const float*)d_in[3];
    const float* Wqa  = (const float*)d_in[4];
    const float* bqa  = (const float*)d_in[5];
    const float* Wk   = (const float*)d_in[6];
    const float* bk   = (const float*)d_in[7];
    const float* Wt   = (const float*)d_in[8];
    const float* bt   = (const float*)d_in[9];
    float* out = (float*)d_out;

    char* ws = (char*)d_ws;
    unsigned short* qk_bf  = (unsigned short*)(ws);                   // [32768][1536] bf16
    unsigned short* hs_bf  = (unsigned short*)(ws + 100663296);       // [32768][768]; dead after gemm1
    unsigned short* W8     = hs_bf;                                   // overlays hs_bf
    unsigned short* Wqk_bf = (unsigned short*)(ws + 150994944);       // [1536][768]
    unsigned short* Wt_bf  = (unsigned short*)(ws + 153354240);       // [768][768]
    unsigned short* Wqa_bf = (unsigned short*)(ws + 154533888);       // [16][768]
    float* bqk    = (float*)(ws + 154558464);                         // [1536]
    float* parts1 = (float*)(ws + 154564608);                         // [512][12][66] = 1.62 MB
    float* parts2 = (float*)(ws + 156186624);                         // [96][8][72]

    prep_all<<<26318, 256, 0, stream>>>(hs, Wq, Wk, Wt, Wqa, bq, bk,
                                        hs_bf, Wqk_bf, Wt_bf, Wqa_bf, bqk);

    // q|k projection: M=32768, N=1536, K=768
    gemm8<<<(M_TOT / 256) * 6, 512, 0, stream>>>(
        hs_bf, Wqk_bf, bqk, qk_bf, 2 * DMODEL, 6);

    qfspool_kernel<<<M_TOT / 64, 256, 0, stream>>>(qk_bf, Wqa_bf, bqa, mask, parts1);
    pool2_kernel<<<NB * NH * 8, 256, 0, stream>>>(parts1, qk_bf, mask, parts2);
    gatedw_kernel<<<NB * 96, 256, 0, stream>>>(parts2, Wt_bf, W8);

    // out = q @ (Wt*pk_b)^T + bt + q : M=32768, N=768 (BN=128), K=768
    gemm8b<<<(M_TOT / 256) * 6, 512, 0, stream>>>(
        qk_bf, W8, bt, out, qk_bf);
}

// Round 5
// 215.573 us; speedup vs baseline: 1.0599x; 1.0599x over previous
//
#include <hip/hip_runtime.h>
#include <cstdint>
#include <cstddef>

#define S_LEN 4096
#define NB 8
#define NH 12
#define DMODEL 768
#define DHEAD 64
#define M_TOT (NB * S_LEN)      /* 32768 */
#define INV_SQRT_DH 0.125f
#define WSZ (DMODEL * DMODEL)

typedef __attribute__((ext_vector_type(4))) float f32x4;
typedef __attribute__((ext_vector_type(8))) short bf16x8;

__device__ inline float bf2f(unsigned short h) {
    union { unsigned int u; float f; } v; v.u = ((unsigned int)h) << 16; return v.f;
}
__device__ inline unsigned short f2bf(float f) {
    union { float f; unsigned int u; } v; v.f = f;
    unsigned int r = v.u + 0x7FFFu + ((v.u >> 16) & 1u);
    return (unsigned short)(r >> 16);
}

__device__ inline void gload_lds16(const unsigned short* gp, void* lp) {
    __builtin_amdgcn_global_load_lds((const __attribute__((address_space(1))) void*)gp,
                                     (__attribute__((address_space(3))) void*)lp,
                                     16, 0, 0);
}

// ---------------- prep: hs cvt + all weights/biases, one launch ----------------
__global__ void prep_all(const float* __restrict__ hs,
                         const float* __restrict__ Wq, const float* __restrict__ Wk,
                         const float* __restrict__ Wt, const float* __restrict__ Wqa,
                         const float* __restrict__ bq, const float* __restrict__ bk,
                         unsigned short* __restrict__ hs_bf,
                         unsigned short* __restrict__ Wqk_bf, unsigned short* __restrict__ Wt_bf,
                         unsigned short* __restrict__ Wqa_bf, float* __restrict__ bqk) {
    int bid = blockIdx.x;
    int t = threadIdx.x;
    if (bid < 24576) {
        int off = bid * 1024 + t * 4;
        float4 v = *(const float4*)(hs + off);
        ushort4 o;
        o.x = f2bf(v.x); o.y = f2bf(v.y); o.z = f2bf(v.z); o.w = f2bf(v.w);
        *(ushort4*)(hs_bf + off) = o;
        return;
    }
    bid -= 24576;
    if (bid < 1728) {
        const float* src = (bid < 576) ? Wq : ((bid < 1152) ? Wk : Wt);
        unsigned short* dst = (bid < 576) ? Wqk_bf : ((bid < 1152) ? (Wqk_bf + WSZ) : Wt_bf);
        int off = (bid % 576) * 1024 + t * 4;
        float4 v = *(const float4*)(src + off);
        ushort4 o;
        o.x = f2bf(v.x); o.y = f2bf(v.y); o.z = f2bf(v.z); o.w = f2bf(v.w);
        *(ushort4*)(dst + off) = o;
    } else if (bid < 1740) {
        int off = (bid - 1728) * 1024 + t * 4;
        int h = off / DMODEL;
        ushort4 o = {0, 0, 0, 0};
        if (h < NH) {
            float4 v = *(const float4*)(Wqa + off);
            o.x = f2bf(v.x); o.y = f2bf(v.y); o.z = f2bf(v.z); o.w = f2bf(v.w);
        }
        *(ushort4*)(Wqa_bf + off) = o;
    } else {
        int off = (bid - 1740) * 1024 + t * 4;
        if (off < 2 * DMODEL) {
            const float* src = (off < DMODEL) ? (bq + off) : (bk + off - DMODEL);
            *(float4*)(bqk + off) = *(const float4*)src;
        }
    }
}

// ---------------- shared phase macros ----------------
#define PH_MID() do { __builtin_amdgcn_s_barrier(); \
    asm volatile("s_waitcnt lgkmcnt(0)"); \
    __builtin_amdgcn_sched_barrier(0); \
    __builtin_amdgcn_s_setprio(1); } while (0)
#define PH_END() do { __builtin_amdgcn_s_setprio(0); \
    __builtin_amdgcn_s_barrier(); } while (0)

// ================= GEMM A: 256x256, 8-load/K-tile (qk projection) =================
#define STG_A(q, kt, BO) gload_lds16(pA + (size_t)((q) * 64) * 768 + (kt) * 64, \
                                     lds + (BO) + (q) * 8192 + wOff)
#define STG_B(q, kt, BO) gload_lds16(pB + (size_t)((q) * 64) * 768 + (kt) * 64, \
                                     lds + (BO) + 32768 + (q) * 8192 + wOff)

#define LD_A(mh, BO) do { _Pragma("unroll") for (int mm = 0; mm < 4; ++mm) { \
    a[mm][0] = *(const bf16x8*)(lds + (BO) + aRd0 + ((mh) * 4 + mm) * 2048); \
    a[mm][1] = *(const bf16x8*)(lds + (BO) + aRd1 + ((mh) * 4 + mm) * 2048); } } while (0)
#define LD_B(nh, BO) do { _Pragma("unroll") for (int nn = 0; nn < 2; ++nn) { \
    b[(nh) * 2 + nn][0] = *(const bf16x8*)(lds + (BO) + bRd0 + ((nh) * 2 + nn) * 2048); \
    b[(nh) * 2 + nn][1] = *(const bf16x8*)(lds + (BO) + bRd1 + ((nh) * 2 + nn) * 2048); } } while (0)
#define MFMAQ(mh, nh) do { _Pragma("unroll") for (int mm = 0; mm < 4; ++mm) \
    _Pragma("unroll") for (int nn = 0; nn < 2; ++nn) { \
        acc[(mh) * 4 + mm][(nh) * 2 + nn] = __builtin_amdgcn_mfma_f32_16x16x32_bf16( \
            a[mm][0], b[(nh) * 2 + nn][0], acc[(mh) * 4 + mm][(nh) * 2 + nn], 0, 0, 0); \
        acc[(mh) * 4 + mm][(nh) * 2 + nn] = __builtin_amdgcn_mfma_f32_16x16x32_bf16( \
            a[mm][1], b[(nh) * 2 + nn][1], acc[(mh) * 4 + mm][(nh) * 2 + nn], 0, 0, 0); } } while (0)

__global__ __launch_bounds__(512, 2) void gemm8(
    const unsigned short* __restrict__ A,
    const unsigned short* __restrict__ Bw,
    const float* __restrict__ bias,
    unsigned short* __restrict__ outBf, int ldoBf,
    int ntn)
{
    __shared__ __align__(16) char lds[131072];

    int nwg = gridDim.x;
    int bid = blockIdx.x;
    int cpx = nwg >> 3;
    int swz = (bid & 7) * cpx + (bid >> 3);
    int bidn = swz % ntn, bidm = swz / ntn;
    int m0 = bidm * 256, n0 = bidn * 256;

    int t = threadIdx.x;
    int w = t >> 6, lane = t & 63;
    int lr = lane & 15, lk = lane >> 4;
    int wr = w >> 2, wc = w & 3;
    int wOff = w << 10;

    int srow = t >> 3;
    int sblk = (t & 7) ^ (srow & 7);
    const unsigned short* pA = A + (size_t)(m0 + srow) * 768 + sblk * 8;
    const unsigned short* pB = Bw + (size_t)(n0 + srow) * 768 + sblk * 8;

    int sx = lr & 7;
    int aRd0 = (wr * 128 + lr) * 128 + ((0 + lk) ^ sx) * 16;
    int aRd1 = (wr * 128 + lr) * 128 + ((4 + lk) ^ sx) * 16;
    int bRd0 = 32768 + (wc * 64 + lr) * 128 + ((0 + lk) ^ sx) * 16;
    int bRd1 = 32768 + (wc * 64 + lr) * 128 + ((4 + lk) ^ sx) * 16;

    f32x4 acc[8][4];
#pragma unroll
    for (int m = 0; m < 8; ++m)
#pragma unroll
        for (int n = 0; n < 4; ++n)
            acc[m][n] = (f32x4){0.f, 0.f, 0.f, 0.f};
    bf16x8 a[4][2], b[4][2];

    STG_A(0, 0, 0); STG_A(1, 0, 0); STG_A(2, 0, 0); STG_A(3, 0, 0);
    STG_B(0, 0, 0); STG_B(1, 0, 0); STG_B(2, 0, 0); STG_B(3, 0, 0);
    STG_A(0, 1, 65536); STG_A(2, 1, 65536);
    STG_B(0, 1, 65536); STG_B(1, 1, 65536); STG_B(2, 1, 65536); STG_B(3, 1, 65536);
    asm volatile("s_waitcnt vmcnt(6)");
    __builtin_amdgcn_s_barrier();

    for (int i = 0; i < 6; ++i) {
        int ktE = 2 * i, ktO = 2 * i + 1;
        int s2 = (i < 5);
        LD_A(0, 0); LD_B(0, 0);
        STG_A(1, ktO, 65536); STG_A(3, ktO, 65536);
        PH_MID(); MFMAQ(0, 0); PH_END();
        LD_B(1, 0);
        if (s2) { STG_A(0, ktE + 2, 0); STG_A(2, ktE + 2, 0); }
        PH_MID(); MFMAQ(0, 1); PH_END();
        LD_A(1, 0);
        if (s2) { STG_B(0, ktE + 2, 0); STG_B(1, ktE + 2, 0); }
        PH_MID(); MFMAQ(1, 1); PH_END();
        if (s2) { STG_B(2, ktE + 2, 0); STG_B(3, ktE + 2, 0); }
        PH_MID(); MFMAQ(1, 0);
        __builtin_amdgcn_s_setprio(0);
        if (s2) { asm volatile("s_waitcnt vmcnt(6)"); }
        else    { asm volatile("s_waitcnt vmcnt(0)"); }
        __builtin_amdgcn_s_barrier();
        LD_A(0, 65536); LD_B(0, 65536);
        if (s2) { STG_A(1, ktE + 2, 0); STG_A(3, ktE + 2, 0); }
        PH_MID(); MFMAQ(0, 0); PH_END();
        LD_B(1, 65536);
        if (s2) { STG_A(0, ktO + 2, 65536); STG_A(2, ktO + 2, 65536); }
        PH_MID(); MFMAQ(0, 1); PH_END();
        LD_A(1, 65536);
        if (s2) { STG_B(0, ktO + 2, 65536); STG_B(1, ktO + 2, 65536); }
        PH_MID(); MFMAQ(1, 1); PH_END();
        if (s2) { STG_B(2, ktO + 2, 65536); STG_B(3, ktO + 2, 65536); }
        PH_MID(); MFMAQ(1, 0);
        __builtin_amdgcn_s_setprio(0);
        if (s2) { asm volatile("s_waitcnt vmcnt(6)"); }
        __builtin_amdgcn_s_barrier();
    }

#pragma unroll
    for (int m = 0; m < 8; ++m) {
        int gr0 = m0 + wr * 128 + m * 16 + lk * 4;
#pragma unroll
        for (int n = 0; n < 4; ++n) {
            int gc = n0 + wc * 64 + n * 16 + lr;
            float bv = bias[gc];
#pragma unroll
            for (int r = 0; r < 4; ++r) {
                int gr = gr0 + r;
                outBf[(size_t)gr * ldoBf + gc] = f2bf(acc[m][n][r] + bv);
            }
        }
    }
}

// ================= GEMM B: 256x128, 3-buffer, 2 phases/K-tile (output GEMM) =================
// 12 K-tiles; tile t reads buf t%3; tile t+2 staged (3+3 loads) during tile t's phases.
// At each tile-boundary exactly 6 loads (tile t+2) outstanding -> vmcnt(6) == tile t+1 ready.
// buf (t+2)%3 last read at tile t-1 (ended at previous boundary barrier) -> WAR safe.
#define STG3_A(q, kt, BO) gload_lds16(pA + (size_t)((q) * 64) * 1536 + (kt) * 64, \
                                      lds + (BO) + (q) * 8192 + wOff)
#define STG3_B(q, kt, BO) gload_lds16(pB + (size_t)((q) * 64) * 768 + (kt) * 64, \
                                      lds + (BO) + 32768 + (q) * 8192 + wOff)
#define LD3_A(mlo, BO) do { _Pragma("unroll") for (int mm = 0; mm < 4; ++mm) { \
    a[mm][0] = *(const bf16x8*)(lds + (BO) + aRd0 + ((mlo) + mm) * 2048); \
    a[mm][1] = *(const bf16x8*)(lds + (BO) + aRd1 + ((mlo) + mm) * 2048); } } while (0)
#define LD3_B(BO) do { _Pragma("unroll") for (int nn = 0; nn < 2; ++nn) { \
    b[nn][0] = *(const bf16x8*)(lds + (BO) + bRd0 + (nn) * 2048); \
    b[nn][1] = *(const bf16x8*)(lds + (BO) + bRd1 + (nn) * 2048); } } while (0)
#define MFMA3(mlo) do { _Pragma("unroll") for (int mm = 0; mm < 4; ++mm) \
    _Pragma("unroll") for (int nn = 0; nn < 2; ++nn) { \
        acc[(mlo) + mm][nn] = __builtin_amdgcn_mfma_f32_16x16x32_bf16( \
            a[mm][0], b[nn][0], acc[(mlo) + mm][nn], 0, 0, 0); \
        acc[(mlo) + mm][nn] = __builtin_amdgcn_mfma_f32_16x16x32_bf16( \
            a[mm][1], b[nn][1], acc[(mlo) + mm][nn], 0, 0, 0); } } while (0)

#define TILE3(t, BO, SO) do { \
    int t2 = (t) + 2; int s2 = (t2 < 12); \
    LD3_A(0, BO); LD3_B(BO); \
    if (s2) { STG3_A(0, t2, SO); STG3_A(1, t2, SO); STG3_A(2, t2, SO); } \
    PH_MID(); MFMA3(0); PH_END(); \
    LD3_A(4, BO); \
    if (s2) { STG3_A(3, t2, SO); STG3_B(0, t2, SO); STG3_B(1, t2, SO); } \
    PH_MID(); MFMA3(4); \
    __builtin_amdgcn_s_setprio(0); \
    if ((t) <= 9) { asm volatile("s_waitcnt vmcnt(6)"); } \
    else if ((t) == 10) { asm volatile("s_waitcnt vmcnt(0)"); } \
    __builtin_amdgcn_s_barrier(); \
} while (0)

__global__ __launch_bounds__(512, 2) void gemm8b(
    const unsigned short* __restrict__ A,      // q in qk_bf, ld 1536
    const unsigned short* __restrict__ W8,     // 8x[768][768] gated Wt
    const float* __restrict__ bias,
    float* __restrict__ outF,
    const unsigned short* __restrict__ resid)  // q, ld 1536
{
    __shared__ __align__(16) char lds[147456];  // 3 x 48 KB

    int nwg = gridDim.x;                       // 768
    int bid = blockIdx.x;
    int cpx = nwg >> 3;
    int swz = (bid & 7) * cpx + (bid >> 3);
    int bidn = swz % 6, bidm = swz / 6;
    int m0 = bidm * 256, n0 = bidn * 128;

    const unsigned short* Bw = W8 + (size_t)(m0 >> 12) * WSZ;

    int t = threadIdx.x;
    int w = t >> 6, lane = t & 63;
    int lr = lane & 15, lk = lane >> 4;
    int wr = w >> 2, wc = w & 3;
    int wOff = w << 10;

    int srow = t >> 3;
    int sblk = (t & 7) ^ (srow & 7);
    const unsigned short* pA = A + (size_t)(m0 + srow) * 1536 + sblk * 8;
    const unsigned short* pB = Bw + (size_t)(n0 + srow) * 768 + sblk * 8;

    int sx = lr & 7;
    int aRd0 = (wr * 128 + lr) * 128 + ((0 + lk) ^ sx) * 16;
    int aRd1 = (wr * 128 + lr) * 128 + ((4 + lk) ^ sx) * 16;
    int bRd0 = 32768 + (wc * 32 + lr) * 128 + ((0 + lk) ^ sx) * 16;
    int bRd1 = 32768 + (wc * 32 + lr) * 128 + ((4 + lk) ^ sx) * 16;

    f32x4 acc[8][2];
#pragma unroll
    for (int m = 0; m < 8; ++m)
#pragma unroll
        for (int n = 0; n < 2; ++n)
            acc[m][n] = (f32x4){0.f, 0.f, 0.f, 0.f};
    bf16x8 a[4][2], b[2][2];

    // prologue: tiles 0 (buf0) and 1 (buf1) fully staged
    STG3_A(0, 0, 0); STG3_A(1, 0, 0); STG3_A(2, 0, 0); STG3_A(3, 0, 0);
    STG3_B(0, 0, 0); STG3_B(1, 0, 0);
    STG3_A(0, 1, 49152); STG3_A(1, 1, 49152); STG3_A(2, 1, 49152); STG3_A(3, 1, 49152);
    STG3_B(0, 1, 49152); STG3_B(1, 1, 49152);
    asm volatile("s_waitcnt vmcnt(6)");
    __builtin_amdgcn_s_barrier();

    for (int ii = 0; ii < 4; ++ii) {
        int tb = ii * 3;
        TILE3(tb + 0, 0,     98304);
        TILE3(tb + 1, 49152, 0);
        TILE3(tb + 2, 98304, 49152);
    }

#pragma unroll
    for (int m = 0; m < 8; ++m) {
        int gr0 = m0 + wr * 128 + m * 16 + lk * 4;
#pragma unroll
        for (int n = 0; n < 2; ++n) {
            int gc = n0 + wc * 32 + n * 16 + lr;
            float bv = bias[gc];
#pragma unroll
            for (int r = 0; r < 4; ++r) {
                int gr = gr0 + r;
                float v = acc[m][n][r] + bv + bf2f(resid[(size_t)gr * 1536 + gc]);
                outF[(size_t)gr * DMODEL + gc] = v;
            }
        }
    }
}

// ---------------- qfs logits: [M,16(12)] = q @ Wqa^T ----------------
__global__ __launch_bounds__(256) void qfs_kernel(
    const unsigned short* __restrict__ q, int ldq,
    const unsigned short* __restrict__ wqa,
    const float* __restrict__ bqa,
    const float* __restrict__ mask,
    float* __restrict__ qfs)
{
    int t = threadIdx.x;
    int w = t >> 6, lane = t & 63;
    int lr = lane & 15, lk = lane >> 4;
    int m0 = blockIdx.x * 64 + w * 16;

    f32x4 acc = (f32x4){0.f, 0.f, 0.f, 0.f};
    for (int k0 = 0; k0 < DMODEL; k0 += 32) {
        bf16x8 av = *(const bf16x8*)&q[(size_t)(m0 + lr) * ldq + k0 + lk * 8];
        bf16x8 bv = *(const bf16x8*)&wqa[lr * DMODEL + k0 + lk * 8];
        acc = __builtin_amdgcn_mfma_f32_16x16x32_bf16(av, bv, acc, 0, 0, 0);
    }
    if (lr < NH) {
        float bv = bqa[lr];
#pragma unroll
        for (int r = 0; r < 4; ++r) {
            int m = m0 + lk * 4 + r;
            int b_ = m >> 12;
            int s = m & (S_LEN - 1);
            qfs[((size_t)b_ * NH + lr) * S_LEN + s] = acc[r] * INV_SQRT_DH + bv + mask[b_ * S_LEN + s];
        }
    }
}

// ---------------- chunked softmax-pool over precomputed logits (pool1) ----------------
__global__ __launch_bounds__(256) void pool1_kernel(
    const float* __restrict__ logits,          // [96][4096]
    const unsigned short* __restrict__ qk,     // ld 1536
    float* __restrict__ parts)                 // [96][8][72]
{
    int bid = blockIdx.x;
    int bh = bid >> 3, c = bid & 7;
    int b = bh / NH, h = bh % NH;
    int s0 = c * 512;
    int t = threadIdx.x;

    __shared__ float w[512];
    __shared__ float red[8];
    __shared__ float part[4][64];

    const float* lg = logits + (size_t)bh * S_LEN + s0;
    float l0 = lg[t], l1 = lg[t + 256];
    float m = fmaxf(l0, l1);
#pragma unroll
    for (int off = 32; off; off >>= 1) m = fmaxf(m, __shfl_xor(m, off));
    if ((t & 63) == 0) red[t >> 6] = m;
    __syncthreads();
    float M = fmaxf(fmaxf(red[0], red[1]), fmaxf(red[2], red[3]));
    float w0 = __expf(l0 - M), w1 = __expf(l1 - M);
    w[t] = w0; w[t + 256] = w1;
    float z = w0 + w1;
#pragma unroll
    for (int off = 32; off; off >>= 1) z += __shfl_xor(z, off);
    if ((t & 63) == 0) red[4 + (t >> 6)] = z;
    __syncthreads();
    float Z = red[4] + red[5] + red[6] + red[7];

    int dblk = t & 7, rgrp = t >> 3;
    const unsigned short* xp = qk + ((size_t)(b * S_LEN + s0)) * 1536 + h * DHEAD + dblk * 8;
    float acc[8];
#pragma unroll
    for (int e = 0; e < 8; ++e) acc[e] = 0.f;
    for (int j = 0; j < 16; ++j) {
        int r = j * 32 + rgrp;
        bf16x8 v = *(const bf16x8*)(xp + (size_t)r * 1536);
        float wr = w[r];
#pragma unroll
        for (int e = 0; e < 8; ++e) acc[e] += wr * bf2f((unsigned short)v[e]);
    }
#pragma unroll
    for (int off = 8; off <= 32; off <<= 1)
#pragma unroll
        for (int e = 0; e < 8; ++e) acc[e] += __shfl_xor(acc[e], off);
    if ((t & 63) < 8) {
#pragma unroll
        for (int e = 0; e < 8; ++e) part[t >> 6][(t & 7) * 8 + e] = acc[e];
    }
    __syncthreads();
    float* dst = parts + ((size_t)bh * 8 + c) * 72;
    if (t < 64) dst[t] = part[0][t] + part[1][t] + part[2][t] + part[3][t];
    else if (t == 64) dst[64] = M;
    else if (t == 65) dst[65] = Z;
}

// ---------------- fused qks+pool2 ----------------
__global__ __launch_bounds__(256) void pool2_kernel(
    const float* __restrict__ parts1,          // [96][8][72]
    const unsigned short* __restrict__ qk,     // ld 1536, k at +768
    const float* __restrict__ mask,
    float* __restrict__ parts2)                // [96][8][72]
{
    int bid = blockIdx.x;
    int bh = bid >> 3, c = bid & 7;
    int b = bh / NH, h = bh % NH;
    int s0 = c * 512;
    int t = threadIdx.x;

    __shared__ float pq[64];
    __shared__ float w[512];
    __shared__ float red[8];
    __shared__ float part[4][64];

    if (t < 64) {
        const float* p1 = parts1 + (size_t)bh * 8 * 72;
        float M1 = -1e30f;
#pragma unroll
        for (int cc = 0; cc < 8; ++cc) M1 = fmaxf(M1, p1[cc * 72 + 64]);
        float Z1 = 0.f, a1 = 0.f;
#pragma unroll
        for (int cc = 0; cc < 8; ++cc) {
            float f = __expf(p1[cc * 72 + 64] - M1);
            Z1 += f * p1[cc * 72 + 65];
            a1 += f * p1[cc * 72 + t];
        }
        pq[t] = a1 / Z1;
    }
    __syncthreads();

    int dblk = t & 7, rgrp = t >> 3;
    float pq8[8];
#pragma unroll
    for (int e = 0; e < 8; ++e) pq8[e] = pq[dblk * 8 + e];

    const unsigned short* kp = qk + ((size_t)(b * S_LEN + s0)) * 1536 + DMODEL + h * DHEAD + dblk * 8;

    for (int j = 0; j < 16; ++j) {
        int r = j * 32 + rgrp;
        bf16x8 v = *(const bf16x8*)(kp + (size_t)r * 1536);
        float d = 0.f;
#pragma unroll
        for (int e = 0; e < 8; ++e) d += bf2f((unsigned short)v[e]) * pq8[e];
        d += __shfl_xor(d, 1); d += __shfl_xor(d, 2); d += __shfl_xor(d, 4);
        if (dblk == 0) w[r] = d * INV_SQRT_DH + mask[b * S_LEN + s0 + r];
    }
    __syncthreads();

    float l0 = w[t], l1 = w[t + 256];
    float m = fmaxf(l0, l1);
#pragma unroll
    for (int off = 32; off; off >>= 1) m = fmaxf(m, __shfl_xor(m, off));
    if ((t & 63) == 0) red[t >> 6] = m;
    __syncthreads();
    float M = fmaxf(fmaxf(red[0], red[1]), fmaxf(red[2], red[3]));
    float w0 = __expf(l0 - M), w1 = __expf(l1 - M);
    float z = w0 + w1;
#pragma unroll
    for (int off = 32; off; off >>= 1) z += __shfl_xor(z, off);
    if ((t & 63) == 0) red[4 + (t >> 6)] = z;
    __syncthreads();
    w[t] = w0; w[t + 256] = w1;
    __syncthreads();
    float Z = red[4] + red[5] + red[6] + red[7];

    float acc[8];
#pragma unroll
    for (int e = 0; e < 8; ++e) acc[e] = 0.f;
    for (int j = 0; j < 16; ++j) {
        int r = j * 32 + rgrp;
        bf16x8 v = *(const bf16x8*)(kp + (size_t)r * 1536);
        float wr = w[r];
#pragma unroll
        for (int e = 0; e < 8; ++e) acc[e] += wr * bf2f((unsigned short)v[e]);
    }
#pragma unroll
    for (int off = 8; off <= 32; off <<= 1)
#pragma unroll
        for (int e = 0; e < 8; ++e) acc[e] += __shfl_xor(acc[e], off);
    if ((t & 63) < 8) {
#pragma unroll
        for (int e = 0; e < 8; ++e) part[t >> 6][(t & 7) * 8 + e] = acc[e];
    }
    __syncthreads();
    float* dst = parts2 + ((size_t)bh * 8 + c) * 72;
    if (t < 64) dst[t] = part[0][t] + part[1][t] + part[2][t] + part[3][t];
    else if (t == 64) dst[64] = M;
    else if (t == 65) dst[65] = Z;
}

// ---------------- gated weights: W8[b] = Wt * pooled_k[b][col] ----------------
__global__ __launch_bounds__(256) void gatedw_kernel(
    const float* __restrict__ parts2,
    const unsigned short* __restrict__ Wt_bf,
    unsigned short* __restrict__ W8)
{
    int bid = blockIdx.x;
    int b = bid / 96, rg = bid % 96;
    int t = threadIdx.x;

    __shared__ float mhc[96], Mh[12], fac[96], zh[12], pk[768];

    if (t < 96) mhc[t] = parts2[((size_t)(b * NH + t / 8) * 8 + (t & 7)) * 72 + 64];
    __syncthreads();
    if (t < 12) {
        float M = -1e30f;
#pragma unroll
        for (int cc = 0; cc < 8; ++cc) M = fmaxf(M, mhc[t * 8 + cc]);
        Mh[t] = M;
    }
    __syncthreads();
    if (t < 96) fac[t] = __expf(mhc[t] - Mh[t / 8]);
    __syncthreads();
    if (t < 12) {
        float Zm = 0.f;
#pragma unroll
        for (int cc = 0; cc < 8; ++cc)
            Zm += fac[t * 8 + cc] * parts2[((size_t)(b * NH + t) * 8 + cc) * 72 + 65];
        zh[t] = Zm;
    }
    __syncthreads();
#pragma unroll
    for (int j = 0; j < 3; ++j) {
        int col = t + 256 * j;
        int h = col >> 6, d = col & 63;
        const float* p2 = parts2 + (size_t)(b * NH + h) * 8 * 72;
        float v = 0.f;
#pragma unroll
        for (int cc = 0; cc < 8; ++cc) v += fac[h * 8 + cc] * p2[cc * 72 + d];
        pk[col] = v / zh[h];
    }
    __syncthreads();
#pragma unroll
    for (int j = 0; j < 3; ++j) {
        int idx = j * 2048 + t * 8;
        int r = rg * 8 + idx / DMODEL, k = idx % DMODEL;
        bf16x8 wv = *(const bf16x8*)(Wt_bf + (size_t)r * DMODEL + k);
        bf16x8 o;
#pragma unroll
        for (int e = 0; e < 8; ++e)
            o[e] = (short)f2bf(bf2f((unsigned short)wv[e]) * pk[k + e]);
        *(bf16x8*)(W8 + (size_t)b * WSZ + (size_t)r * DMODEL + k) = o;
    }
}

// ---------------- launch ----------------
extern "C" void kernel_launch(void* const* d_in, const int* in_sizes, int n_in,
                              void* d_out, int out_size, void* d_ws, size_t ws_size,
                              hipStream_t stream) {
    const float* hs   = (const float*)d_in[0];
    const float* mask = (const float*)d_in[1];
    const float* Wq   = (const float*)d_in[2];
    const float* bq   = (const float*)d_in[3];
    const float* Wqa  = (const float*)d_in[4];
    const float* bqa  = (const float*)d_in[5];
    const float* Wk   = (const float*)d_in[6];
    const float* bk   = (const float*)d_in[7];
    const float* Wt   = (const float*)d_in[8];
    const float* bt   = (const float*)d_in[9];
    float* out = (float*)d_out;

    char* ws = (char*)d_ws;
    unsigned short* qk_bf  = (unsigned short*)(ws);                   // [32768][1536] bf16
    unsigned short* hs_bf  = (unsigned short*)(ws + 100663296);       // [32768][768]; dead after gemm1
    unsigned short* W8     = hs_bf;                                   // overlays hs_bf
    unsigned short* Wqk_bf = (unsigned short*)(ws + 150994944);       // [1536][768]
    unsigned short* Wt_bf  = (unsigned short*)(ws + 153354240);       // [768][768]
    unsigned short* Wqa_bf = (unsigned short*)(ws + 154533888);       // [16][768]
    float* bqk    = (float*)(ws + 154558464);                         // [1536]
    float* qfs    = (float*)(ws + 154564608);                         // [96][4096]
    float* parts1 = (float*)(ws + 156137472);                         // [96][8][72]
    float* parts2 = (float*)(ws + 156358656);                         // [96][8][72]

    prep_all<<<26318, 256, 0, stream>>>(hs, Wq, Wk, Wt, Wqa, bq, bk,
                                        hs_bf, Wqk_bf, Wt_bf, Wqa_bf, bqk);

    // q|k projection: M=32768, N=1536, K=768
    gemm8<<<(M_TOT / 256) * 6, 512, 0, stream>>>(
        hs_bf, Wqk_bf, bqk, qk_bf, 2 * DMODEL, 6);

    qfs_kernel<<<M_TOT / 64, 256, 0, stream>>>(qk_bf, 2 * DMODEL, Wqa_bf, bqa, mask, qfs);
    pool1_kernel<<<NB * NH * 8, 256, 0, stream>>>(qfs, qk_bf, parts1);
    pool2_kernel<<<NB * NH * 8, 256, 0, stream>>>(parts1, qk_bf, mask, parts2);
    gatedw_kernel<<<NB * 96, 256, 0, stream>>>(parts2, Wt_bf, W8);

    // out = q @ (Wt*pk_b)^T + bt + q : M=32768, N=768 (BN=128, 3-buf), K=768
    gemm8b<<<(M_TOT / 256) * 6, 512, 0, stream>>>(
        qk_bf, W8, bt, out, qk_bf);
}